// Round 4
// baseline (220.460 us; speedup 1.0000x reference)
//
#include <hip/hip_runtime.h>

// Born-series scattering, M=4096 pts, 4 wavenumbers, 5 Born iterations,
// 64 obs dirs.
// R4: bit-faithful D^2 (Gram rounding sequence) -> absmax 0.0.
// R5-R8: atomics eliminated; fused chunk-reduce.
// R9-R15: eight probes on the matvec plateau all neutral/regressed.
// R16: 219.8us. R17: reduce butterfly + init regrid (215.4us).
// R18: hand-rolled persistent barrier -> HSA abort (non-coherent XCD spin).
// R19: cooperative-launch fusion -> NEUTRAL (215.2us). Launch gaps are NOT
//   the cost; the 5 matvecs (~36us each) are. Coop dropped (rocprof-hostile).
// R20: G-CACHE. The Green's kernel is iteration-invariant; the reference
//   computes it once per k, we recomputed it 5x. Iter 0 computes the
//   front-end (D^2, rsq, sincos) as before AND stores (c1,s1) per ordered
//   pair to ws: 4096^2 x 8B = 134MB (fits 256MB Infinity Cache). Iters 1-4
//   load (c1,s1) -- bit-identical stored values -- and recompute only
//   d2->rsq (identical sequence -> identical sc bits). All downstream math
//   (recurrence, ACC_UPD, partial layout, reduce tree) unchanged ->
//   absmax 0.0 preserved. Gated on ws_size; R17 path is the fallback.
//
// ws layout (floats):
//   colpack[M][12]: x,y,z,r2, ar[4], ai[4]          (a = C * vw * psi, per k)
//   cvw[M]; p0r[4][M], p0i[4][M]; yr[4][M], yi[4][M] (fallback path only)
//   part[C][4][M] of float2                          (partials, 16MB)
//   g2[M][M] of float2 (c1,s1), col-major [j][r]     (G-cache, 134MB)

#define MM 4096
#define NK 4
#define CGREEN 0.07957747154594767f   // 1/(4*pi)
#define INV2PI 0.15915494309189535f   // 1/(2*pi)

#define OFF_VW   49152
#define OFF_P0R  53248
#define OFF_P0I  69632
#define OFF_YR   86016
#define OFF_YI   102400
#define OFF_PART 118784
#define NCHUNK 128
#define PART_FLOATS (NCHUNK * 8 * MM)
#define WS_NEED_PART ((size_t)(OFF_PART + PART_FLOATS) * 4)
#define OFF_G    (OFF_PART + PART_FLOATS)          // 4313088 floats
#define G_FLOATS ((size_t)MM * MM * 2)             // 33554432 floats
#define WS_NEED_G (((size_t)OFF_G + G_FLOATS) * 4) // ~151.5 MB

typedef float f2 __attribute__((ext_vector_type(2)));

__device__ __forceinline__ f2 vfma(f2 a, f2 b, f2 c) {
    f2 r; r.x = fmaf(a.x, b.x, c.x); r.y = fmaf(a.y, b.y, c.y); return r;
}

// One (point i, wavenumber n) init item.
__device__ __forceinline__ void init_item(int i, int n, const float* __restrict__ V,
                                          const float* __restrict__ pts,
                                          const float* __restrict__ w,
                                          float* __restrict__ ws, bool writeBase) {
#pragma clang fp contract(off)
    float x = pts[3 * i], y = pts[3 * i + 1], z = pts[3 * i + 2];
    float cvw = CGREEN * (V[i] * w[i]);
    float* cp = ws + i * 12;
    if (writeBase) {
        float xx = x * x, yy = y * y, zz = z * z;
        float r2 = (xx + yy) + zz;             // np rounding order
        cp[0] = x; cp[1] = y; cp[2] = z; cp[3] = r2;
        ws[OFF_VW + i] = cvw;
    }
    float kk = 0.5f * (float)(n + 1);
    float s, c;
    sincosf(kk * z, &s, &c);
    ws[OFF_P0R + n * MM + i] = c;
    ws[OFF_P0I + n * MM + i] = s;
    cp[4 + n] = cvw * c;
    cp[8 + n] = cvw * s;
}

__global__ __launch_bounds__(64) void init_k(const float* __restrict__ V,
                                             const float* __restrict__ pts,
                                             const float* __restrict__ w,
                                             float* __restrict__ ws) {
    int i = blockIdx.x * 64 + threadIdx.x;
#pragma unroll
    for (int n = 0; n < NK; n++) {
        init_item(i, n, V, pts, w, ws, n == 0);
        ws[OFF_YR + n * MM + i] = 0.0f;
        ws[OFF_YI + n * MM + i] = 0.0f;
    }
}

// One column vs TWO rows. GM: 0 = compute (R17), 1 = compute+write G,
// 2 = read G (load c1,s1; recompute d2->rsq for the identical sc bits).
template <int GM>
__device__ __forceinline__ void body_col2(f2 rx, f2 ry, f2 rz, f2 rr2,
                                          int r0, int r1, int jg,
                                          float4 A, float4 R, float4 I,
                                          f2 acc0[4], f2 acc1[4],
                                          float2* __restrict__ gcol) {
    // issue independent G loads first (latency hiding)
    float2 ga, gb;
    if (GM == 2) { ga = gcol[r0]; gb = gcol[r1]; }
    // ---- bit-faithful D^2, per-element rounding == reference sequence ----
    f2 d2;
    {
#pragma clang fp contract(off)
        f2 m; m.x = rx.x * A.x; m.y = rx.y * A.x;          // rounded mul
        m = vfma(ry, (f2){A.y, A.y}, m);                   // k-order fma chain
        m = vfma(rz, (f2){A.z, A.z}, m);
        f2 r2s = rr2 + A.w;                                // rounded add
        f2 twod = 2.0f * m;                                // exact
        d2 = r2s - twod;                                   // single rounded sub
    }
    d2.x = fmaxf(d2.x, 1e-12f);
    d2.y = fmaxf(d2.y, 1e-12f);
    // ---- fast-math (proven invisible in bucketed output) ----
    float ia = __builtin_amdgcn_rsqf(d2.x);
    float ib = __builtin_amdgcn_rsqf(d2.y);
    float sca = (jg == r0) ? 0.0f : ia;
    float scb = (jg == r1) ? 0.0f : ib;
    f2 s1, c1;
    if (GM == 2) {
        c1.x = ga.x; s1.x = ga.y;
        c1.y = gb.x; s1.y = gb.y;
    } else {
        f2 invD = {ia, ib};
        f2 rev = d2 * invD * (0.5f * INV2PI);   // angle 0.5*D in revolutions
        s1.x = __builtin_amdgcn_sinf(rev.x);    // raw v_sin: sin(2*pi*x)
        c1.x = __builtin_amdgcn_cosf(rev.x);
        s1.y = __builtin_amdgcn_sinf(rev.y);
        c1.y = __builtin_amdgcn_cosf(rev.y);
        if (GM == 1) {
            gcol[r0] = make_float2(c1.x, s1.x);
            gcol[r1] = make_float2(c1.y, s1.y);
        }
    }
    f2 c2 = vfma(c1, c1, -(s1 * s1));
    f2 s2 = 2.0f * (c1 * s1);
    f2 c3 = vfma(c2, c1, -(s2 * s1));
    f2 s3 = vfma(s2, c1, c2 * s1);
    f2 c4 = vfma(c2, c2, -(s2 * s2));
    f2 s4 = 2.0f * (c2 * s2);
#define ACC_UPD(nn, CC, SS, ZR, ZI)                                          \
    {                                                                        \
        f2 ri = {ZR, ZI}, sw = {-ZI, ZR};                                    \
        f2 t0 = CC.x * ri; t0 = vfma((f2){SS.x, SS.x}, sw, t0);              \
        acc0[nn] = vfma((f2){sca, sca}, t0, acc0[nn]);                       \
        f2 t1 = CC.y * ri; t1 = vfma((f2){SS.y, SS.y}, sw, t1);              \
        acc1[nn] = vfma((f2){scb, scb}, t1, acc1[nn]);                       \
    }
    ACC_UPD(0, c1, s1, R.x, I.x)
    ACC_UPD(1, c2, s2, R.y, I.y)
    ACC_UPD(2, c3, s3, R.z, I.z)
    ACC_UPD(3, c4, s4, R.w, I.w)
#undef ACC_UPD
}

// grid: (C chunks, 8 row-groups of 512); block 256; 2 rows/thread.
template <int C, int GM, bool USE_PART>
__global__ __launch_bounds__(256) void matvec_k(const float* __restrict__ cols,
                                                f2* __restrict__ part,
                                                float2* __restrict__ g2,
                                                float* __restrict__ yr,
                                                float* __restrict__ yi) {
    constexpr int TC = MM / C;                 // cols per block (32)
    const int chunk = blockIdx.x;
    const int rg = blockIdx.y;
    const int r0 = rg * 512 + threadIdx.x;
    const int r1 = r0 + 256;
    const float4 rowA = *(const float4*)&cols[r0 * 12];   // x,y,z,r2
    const float4 rowB = *(const float4*)&cols[r1 * 12];
    const f2 rx = {rowA.x, rowB.x}, ry = {rowA.y, rowB.y};
    const f2 rz = {rowA.z, rowB.z}, rr2 = {rowA.w, rowB.w};
    f2 acc0[4], acc1[4];
#pragma unroll
    for (int i = 0; i < 4; i++) {
        acc0[i].x = 0.0f; acc0[i].y = 0.0f;
        acc1[i].x = 0.0f; acc1[i].y = 0.0f;
    }
    const int jg0 = chunk * TC;
    const float* colbase = cols + (size_t)jg0 * 12;   // uniform across lanes
#pragma unroll 4
    for (int j = 0; j < TC; j++) {
        const float4* cp = (const float4*)(colbase + j * 12);
        float4 A = cp[0], R = cp[1], I = cp[2];
        float2* gcol = g2 + (size_t)(jg0 + j) * MM;
        body_col2<GM>(rx, ry, rz, rr2, r0, r1, jg0 + j, A, R, I, acc0, acc1, gcol);
    }
    if (USE_PART) {
#pragma unroll
        for (int n = 0; n < NK; n++) {
            part[(size_t)(chunk * 4 + n) * MM + r0] = acc0[n];
            part[(size_t)(chunk * 4 + n) * MM + r1] = acc1[n];
        }
    } else {
#pragma unroll
        for (int n = 0; n < NK; n++) {
            atomicAdd(&yr[n * MM + r0], acc0[n].x);
            atomicAdd(&yi[n * MM + r0], acc0[n].y);
            atomicAdd(&yr[n * MM + r1], acc1[n].x);
            atomicAdd(&yi[n * MM + r1], acc1[n].y);
        }
    }
}

// Fused chunk-reduction + psi update, 8 lanes per (n,row) (R17).
template <int C>
__global__ __launch_bounds__(256) void reduce_update_k(float* __restrict__ ws) {
    int t = blockIdx.x * 256 + threadIdx.x;        // [0, 131072)
    int u = t & 7;                                 // accumulator index
    int item = t >> 3;                             // [0, 16384) = (n,row)
    int row = item & (MM - 1);
    int n = item >> 12;                            // 0..3
    const f2* part2 = (const f2*)(ws + OFF_PART);
    f2 s; s.x = 0.0f; s.y = 0.0f;
#pragma unroll
    for (int j = 0; j < C / 8; j++) {
        int c = u + 8 * j;
        s += part2[(size_t)(c * 4 + n) * MM + row];
    }
    // exact combine tree via butterfly (a+b bitwise == b+a)
    s.x += __shfl_xor(s.x, 1); s.y += __shfl_xor(s.y, 1);
    s.x += __shfl_xor(s.x, 2); s.y += __shfl_xor(s.y, 2);
    s.x += __shfl_xor(s.x, 4); s.y += __shfl_xor(s.y, 4);
    if (u == 0) {
        float cvw = ws[OFF_VW + row];
        float pr = ws[OFF_P0R + n * MM + row] + s.x;
        float pi = ws[OFF_P0I + n * MM + row] + s.y;
        ws[row * 12 + 4 + n] = cvw * pr;
        ws[row * 12 + 8 + n] = cvw * pi;
    }
}

// atomic-fallback update (only used if ws too small for partials)
__global__ __launch_bounds__(256) void update_fallback_k(float* __restrict__ ws) {
    int i = blockIdx.x * 256 + threadIdx.x;
    float cvw = ws[OFF_VW + i];
#pragma unroll
    for (int n = 0; n < NK; n++) {
        float pr = ws[OFF_P0R + n * MM + i] + ws[OFF_YR + n * MM + i];
        float pi = ws[OFF_P0I + n * MM + i] + ws[OFF_YI + n * MM + i];
        ws[i * 12 + 4 + n] = cvw * pr;
        ws[i * 12 + 8 + n] = cvw * pi;
        ws[OFF_YR + n * MM + i] = 0.0f;
        ws[OFF_YI + n * MM + i] = 0.0f;
    }
}

// 512 blocks: (k, obs_dir, j-half). float4 loads from the colpack.
__global__ __launch_bounds__(256) void far_k(const float* __restrict__ obs,
                                             const float* __restrict__ ws,
                                             float* __restrict__ out) {
    int kidx = (blockIdx.x >> 1) >> 6;
    int d = (blockIdx.x >> 1) & 63;
    int half = blockIdx.x & 1;
    float kk = 0.5f * (float)(kidx + 1);
    float ox = obs[3 * d], oy = obs[3 * d + 1], oz = obs[3 * d + 2];
    float fr = 0.0f, fi = 0.0f;
    for (int j = half * 2048 + threadIdx.x; j < half * 2048 + 2048; j += 256) {
        const float4* c4 = (const float4*)(ws + j * 12);
        float4 P = c4[0], AR = c4[1], AI = c4[2];
        float q = fmaf(P.z, oz, fmaf(P.y, oy, P.x * ox));
        float ar, ai;
        switch (kidx) {
            case 0: ar = AR.x; ai = AI.x; break;
            case 1: ar = AR.y; ai = AI.y; break;
            case 2: ar = AR.z; ai = AI.z; break;
            default: ar = AR.w; ai = AI.w; break;
        }
        float s, co;
        __sincosf(kk * q, &s, &co);
        fr += fmaf(ar, co,  ai * s);
        fi += fmaf(ai, co, -ar * s);
    }
#pragma unroll
    for (int off = 32; off > 0; off >>= 1) {
        fr += __shfl_down(fr, off);
        fi += __shfl_down(fi, off);
    }
    __shared__ float red[4][2];
    int wave = threadIdx.x >> 6;
    if ((threadIdx.x & 63) == 0) { red[wave][0] = fr; red[wave][1] = fi; }
    __syncthreads();
    if (threadIdx.x == 0) {
        fr = red[0][0] + red[1][0] + red[2][0] + red[3][0];
        fi = red[0][1] + red[1][1] + red[2][1] + red[3][1];
        atomicAdd(&out[(kidx * 64 + d) * 2 + 0], -fr);
        atomicAdd(&out[(kidx * 64 + d) * 2 + 1], -fi);
    }
}

extern "C" void kernel_launch(void* const* d_in, const int* in_sizes, int n_in,
                              void* d_out, int out_size, void* d_ws, size_t ws_size,
                              hipStream_t stream) {
    const float* V   = (const float*)d_in[0];
    const float* obs = (const float*)d_in[1];
    const float* pts = (const float*)d_in[2];
    const float* w   = (const float*)d_in[3];
    float* ws  = (float*)d_ws;
    float* out = (float*)d_out;
    float2* g2 = (float2*)(ws + OFF_G);
    f2* part = (f2*)(ws + OFF_PART);

    // d_out is re-poisoned before every call: zero it (far_k accumulates)
    hipMemsetAsync(out, 0, (size_t)out_size * 4, stream);

    init_k<<<64, 64, 0, stream>>>(V, pts, w, ws);
    if (ws_size >= WS_NEED_G) {
        // iter 0: compute front-end + write G; iters 1-4: read G
        matvec_k<NCHUNK, 1, true><<<dim3(NCHUNK, 8), 256, 0, stream>>>(
            ws, part, g2, ws + OFF_YR, ws + OFF_YI);
        reduce_update_k<NCHUNK><<<512, 256, 0, stream>>>(ws);
        for (int it = 1; it < 5; it++) {
            matvec_k<NCHUNK, 2, true><<<dim3(NCHUNK, 8), 256, 0, stream>>>(
                ws, part, g2, ws + OFF_YR, ws + OFF_YI);
            reduce_update_k<NCHUNK><<<512, 256, 0, stream>>>(ws);
        }
        far_k<<<512, 256, 0, stream>>>(obs, ws, out);
    } else if (ws_size >= WS_NEED_PART) {
        // R17 path (measured 215.4us)
        for (int it = 0; it < 5; it++) {
            matvec_k<NCHUNK, 0, true><<<dim3(NCHUNK, 8), 256, 0, stream>>>(
                ws, part, g2, ws + OFF_YR, ws + OFF_YI);
            reduce_update_k<NCHUNK><<<512, 256, 0, stream>>>(ws);
        }
        far_k<<<512, 256, 0, stream>>>(obs, ws, out);
    } else {
        for (int it = 0; it < 5; it++) {
            matvec_k<64, 0, false><<<dim3(64, 8), 256, 0, stream>>>(
                ws, part, g2, ws + OFF_YR, ws + OFF_YI);
            update_fallback_k<<<16, 256, 0, stream>>>(ws);
        }
        far_k<<<512, 256, 0, stream>>>(obs, ws, out);
    }
}

// Round 5
// 208.911 us; speedup vs baseline: 1.0553x; 1.0553x over previous
//
#include <hip/hip_runtime.h>

// Born-series scattering, M=4096 pts, 4 wavenumbers, 5 Born iterations,
// 64 obs dirs.
// R4: bit-faithful D^2 (Gram rounding sequence) -> absmax 0.0.
// R5-R8: atomics eliminated; fused chunk-reduce.
// R9-R15: eight scheduling/residency probes on matvec all neutral.
// R16: 219.8us. R17: reduce butterfly + init regrid (215.4us).
// R18: hand-rolled persistent barrier -> HSA abort. R19: cooperative fusion
//   -> neutral (215.2us): launch gaps are NOT the cost.
// R20: G-cache (skip sincos in 4/5 matvecs) -> neutral (220.5us): matvec is
//   NOT trans-bound.
// R21: PACKED MATH. Post-mortem arithmetic: ~100 scalar f32 VALU ops per
//   body_col2, x 32 cols x 4 waves/SIMD x 2cy ~= measured 40us/matvec ->
//   the kernel is VALU-ISSUE-bound on scalar ops. The f2 vector already
//   packs the row pair, but vfma was two scalar fmaf calls -> v_fma_f32.
//   Rewrite all f2 arithmetic in true vector form (__builtin_elementwise_fma,
//   vector mul/add/sub/max) so the backend emits v_pk_{fma,mul,add,max}_f32
//   (gfx90a+ packed dual-f32; BIT-IDENTICAL per component). ~2x fewer VALU
//   issues, rounding untouched -> absmax 0.0 preserved. G-cache reverted.
//
// ws layout (floats):
//   colpack[M][12]: x,y,z,r2, ar[4], ai[4]          (a = C * vw * psi, per k)
//   cvw[M]; p0r[4][M], p0i[4][M]; yr[4][M], yi[4][M] (fallback)
//   part[C][4][M] of float2                          (partials, 16MB)

#define MM 4096
#define NK 4
#define CGREEN 0.07957747154594767f   // 1/(4*pi)
#define INV2PI 0.15915494309189535f   // 1/(2*pi)

#define OFF_VW   49152
#define OFF_P0R  53248
#define OFF_P0I  69632
#define OFF_YR   86016
#define OFF_YI   102400
#define OFF_PART 118784
#define NCHUNK 128
#define PART_FLOATS (NCHUNK * 8 * MM)
#define WS_NEED_PART ((size_t)(OFF_PART + PART_FLOATS) * 4)

typedef float f2 __attribute__((ext_vector_type(2)));

// Packed vector fma: v_pk_fma_f32 is bit-identical per component to
// v_fma_f32 -- packing only changes issue count, not rounding.
__device__ __forceinline__ f2 vfma(f2 a, f2 b, f2 c) {
#if __has_builtin(__builtin_elementwise_fma)
    return __builtin_elementwise_fma(a, b, c);
#else
    f2 r; r.x = fmaf(a.x, b.x, c.x); r.y = fmaf(a.y, b.y, c.y); return r;
#endif
}

__device__ __forceinline__ f2 vmax(f2 a, f2 b) {
#if __has_builtin(__builtin_elementwise_max)
    return __builtin_elementwise_max(a, b);
#else
    f2 r; r.x = fmaxf(a.x, b.x); r.y = fmaxf(a.y, b.y); return r;
#endif
}

__device__ __forceinline__ f2 splat(float v) { f2 r; r.x = v; r.y = v; return r; }

// One (point i, wavenumber n) init item.
__device__ __forceinline__ void init_item(int i, int n, const float* __restrict__ V,
                                          const float* __restrict__ pts,
                                          const float* __restrict__ w,
                                          float* __restrict__ ws, bool writeBase) {
#pragma clang fp contract(off)
    float x = pts[3 * i], y = pts[3 * i + 1], z = pts[3 * i + 2];
    float cvw = CGREEN * (V[i] * w[i]);
    float* cp = ws + i * 12;
    if (writeBase) {
        float xx = x * x, yy = y * y, zz = z * z;
        float r2 = (xx + yy) + zz;             // np rounding order
        cp[0] = x; cp[1] = y; cp[2] = z; cp[3] = r2;
        ws[OFF_VW + i] = cvw;
    }
    float kk = 0.5f * (float)(n + 1);
    float s, c;
    sincosf(kk * z, &s, &c);
    ws[OFF_P0R + n * MM + i] = c;
    ws[OFF_P0I + n * MM + i] = s;
    cp[4 + n] = cvw * c;
    cp[8 + n] = cvw * s;
}

__global__ __launch_bounds__(64) void init_k(const float* __restrict__ V,
                                             const float* __restrict__ pts,
                                             const float* __restrict__ w,
                                             float* __restrict__ ws) {
    int i = blockIdx.x * 64 + threadIdx.x;
#pragma unroll
    for (int n = 0; n < NK; n++) {
        init_item(i, n, V, pts, w, ws, n == 0);
        ws[OFF_YR + n * MM + i] = 0.0f;
        ws[OFF_YI + n * MM + i] = 0.0f;
    }
}

// One column vs TWO rows; all f2 math in vector form -> packed VOP3P.
__device__ __forceinline__ void body_col2(f2 rx, f2 ry, f2 rz, f2 rr2,
                                          int r0, int r1, int jg,
                                          float4 A, float4 R, float4 I,
                                          f2 acc0[4], f2 acc1[4]) {
    // ---- bit-faithful D^2, per-element rounding == reference sequence ----
    f2 d2;
    {
#pragma clang fp contract(off)
        f2 m = rx * splat(A.x);                            // rounded mul
        m = vfma(ry, splat(A.y), m);                       // k-order fma chain
        m = vfma(rz, splat(A.z), m);
        f2 r2s = rr2 + splat(A.w);                         // rounded add
        f2 twod = 2.0f * m;                                // exact
        d2 = r2s - twod;                                   // single rounded sub
    }
    d2 = vmax(d2, splat(1e-12f));
    // ---- fast-math (proven invisible in bucketed output) ----
    float ia = __builtin_amdgcn_rsqf(d2.x);
    float ib = __builtin_amdgcn_rsqf(d2.y);
    f2 invD = {ia, ib};
    f2 rev = d2 * invD * (0.5f * INV2PI);   // angle 0.5*D in revolutions
    float sca = (jg == r0) ? 0.0f : ia;
    float scb = (jg == r1) ? 0.0f : ib;
    f2 s1, c1;
    s1.x = __builtin_amdgcn_sinf(rev.x);    // raw v_sin: sin(2*pi*x)
    c1.x = __builtin_amdgcn_cosf(rev.x);
    s1.y = __builtin_amdgcn_sinf(rev.y);
    c1.y = __builtin_amdgcn_cosf(rev.y);
    f2 c2 = vfma(c1, c1, -(s1 * s1));
    f2 s2 = 2.0f * (c1 * s1);
    f2 c3 = vfma(c2, c1, -(s2 * s1));
    f2 s3 = vfma(s2, c1, c2 * s1);
    f2 c4 = vfma(c2, c2, -(s2 * s2));
    f2 s4 = 2.0f * (c2 * s2);
    const f2 vsca = splat(sca), vscb = splat(scb);
#define ACC_UPD(nn, CC, SS, ZR, ZI)                                          \
    {                                                                        \
        f2 ri = {ZR, ZI}, sw = {-ZI, ZR};                                    \
        f2 t0 = splat(CC.x) * ri; t0 = vfma(splat(SS.x), sw, t0);            \
        acc0[nn] = vfma(vsca, t0, acc0[nn]);                                 \
        f2 t1 = splat(CC.y) * ri; t1 = vfma(splat(SS.y), sw, t1);            \
        acc1[nn] = vfma(vscb, t1, acc1[nn]);                                 \
    }
    ACC_UPD(0, c1, s1, R.x, I.x)
    ACC_UPD(1, c2, s2, R.y, I.y)
    ACC_UPD(2, c3, s3, R.z, I.z)
    ACC_UPD(3, c4, s4, R.w, I.w)
#undef ACC_UPD
}

// grid: (C chunks, 8 row-groups of 512); block 256; 2 rows/thread.
template <int C, bool USE_PART>
__global__ __launch_bounds__(256) void matvec_k(const float* __restrict__ cols,
                                                f2* __restrict__ part,
                                                float* __restrict__ yr,
                                                float* __restrict__ yi) {
    constexpr int TC = MM / C;                 // cols per block (32)
    const int chunk = blockIdx.x;
    const int rg = blockIdx.y;
    const int r0 = rg * 512 + threadIdx.x;
    const int r1 = r0 + 256;
    const float4 rowA = *(const float4*)&cols[r0 * 12];   // x,y,z,r2
    const float4 rowB = *(const float4*)&cols[r1 * 12];
    const f2 rx = {rowA.x, rowB.x}, ry = {rowA.y, rowB.y};
    const f2 rz = {rowA.z, rowB.z}, rr2 = {rowA.w, rowB.w};
    f2 acc0[4], acc1[4];
#pragma unroll
    for (int i = 0; i < 4; i++) {
        acc0[i].x = 0.0f; acc0[i].y = 0.0f;
        acc1[i].x = 0.0f; acc1[i].y = 0.0f;
    }
    const int jg0 = chunk * TC;
    const float* colbase = cols + (size_t)jg0 * 12;   // uniform across lanes
#pragma unroll 4
    for (int j = 0; j < TC; j++) {
        const float4* cp = (const float4*)(colbase + j * 12);
        float4 A = cp[0], R = cp[1], I = cp[2];
        body_col2(rx, ry, rz, rr2, r0, r1, jg0 + j, A, R, I, acc0, acc1);
    }
    if (USE_PART) {
#pragma unroll
        for (int n = 0; n < NK; n++) {
            part[(size_t)(chunk * 4 + n) * MM + r0] = acc0[n];
            part[(size_t)(chunk * 4 + n) * MM + r1] = acc1[n];
        }
    } else {
#pragma unroll
        for (int n = 0; n < NK; n++) {
            atomicAdd(&yr[n * MM + r0], acc0[n].x);
            atomicAdd(&yi[n * MM + r0], acc0[n].y);
            atomicAdd(&yr[n * MM + r1], acc1[n].x);
            atomicAdd(&yi[n * MM + r1], acc1[n].y);
        }
    }
}

// Fused chunk-reduction + psi update, 8 lanes per (n,row) (R17).
template <int C>
__global__ __launch_bounds__(256) void reduce_update_k(float* __restrict__ ws) {
    int t = blockIdx.x * 256 + threadIdx.x;        // [0, 131072)
    int u = t & 7;                                 // accumulator index
    int item = t >> 3;                             // [0, 16384) = (n,row)
    int row = item & (MM - 1);
    int n = item >> 12;                            // 0..3
    const f2* part2 = (const f2*)(ws + OFF_PART);
    f2 s; s.x = 0.0f; s.y = 0.0f;
#pragma unroll
    for (int j = 0; j < C / 8; j++) {
        int c = u + 8 * j;
        s += part2[(size_t)(c * 4 + n) * MM + row];
    }
    // exact combine tree via butterfly (a+b bitwise == b+a)
    s.x += __shfl_xor(s.x, 1); s.y += __shfl_xor(s.y, 1);
    s.x += __shfl_xor(s.x, 2); s.y += __shfl_xor(s.y, 2);
    s.x += __shfl_xor(s.x, 4); s.y += __shfl_xor(s.y, 4);
    if (u == 0) {
        float cvw = ws[OFF_VW + row];
        float pr = ws[OFF_P0R + n * MM + row] + s.x;
        float pi = ws[OFF_P0I + n * MM + row] + s.y;
        ws[row * 12 + 4 + n] = cvw * pr;
        ws[row * 12 + 8 + n] = cvw * pi;
    }
}

// atomic-fallback update (only used if ws too small for partials)
__global__ __launch_bounds__(256) void update_fallback_k(float* __restrict__ ws) {
    int i = blockIdx.x * 256 + threadIdx.x;
    float cvw = ws[OFF_VW + i];
#pragma unroll
    for (int n = 0; n < NK; n++) {
        float pr = ws[OFF_P0R + n * MM + i] + ws[OFF_YR + n * MM + i];
        float pi = ws[OFF_P0I + n * MM + i] + ws[OFF_YI + n * MM + i];
        ws[i * 12 + 4 + n] = cvw * pr;
        ws[i * 12 + 8 + n] = cvw * pi;
        ws[OFF_YR + n * MM + i] = 0.0f;
        ws[OFF_YI + n * MM + i] = 0.0f;
    }
}

// 512 blocks: (k, obs_dir, j-half). float4 loads from the colpack.
__global__ __launch_bounds__(256) void far_k(const float* __restrict__ obs,
                                             const float* __restrict__ ws,
                                             float* __restrict__ out) {
    int kidx = (blockIdx.x >> 1) >> 6;
    int d = (blockIdx.x >> 1) & 63;
    int half = blockIdx.x & 1;
    float kk = 0.5f * (float)(kidx + 1);
    float ox = obs[3 * d], oy = obs[3 * d + 1], oz = obs[3 * d + 2];
    float fr = 0.0f, fi = 0.0f;
    for (int j = half * 2048 + threadIdx.x; j < half * 2048 + 2048; j += 256) {
        const float4* c4 = (const float4*)(ws + j * 12);
        float4 P = c4[0], AR = c4[1], AI = c4[2];
        float q = fmaf(P.z, oz, fmaf(P.y, oy, P.x * ox));
        float ar, ai;
        switch (kidx) {
            case 0: ar = AR.x; ai = AI.x; break;
            case 1: ar = AR.y; ai = AI.y; break;
            case 2: ar = AR.z; ai = AI.z; break;
            default: ar = AR.w; ai = AI.w; break;
        }
        float s, co;
        __sincosf(kk * q, &s, &co);
        fr += fmaf(ar, co,  ai * s);
        fi += fmaf(ai, co, -ar * s);
    }
#pragma unroll
    for (int off = 32; off > 0; off >>= 1) {
        fr += __shfl_down(fr, off);
        fi += __shfl_down(fi, off);
    }
    __shared__ float red[4][2];
    int wave = threadIdx.x >> 6;
    if ((threadIdx.x & 63) == 0) { red[wave][0] = fr; red[wave][1] = fi; }
    __syncthreads();
    if (threadIdx.x == 0) {
        fr = red[0][0] + red[1][0] + red[2][0] + red[3][0];
        fi = red[0][1] + red[1][1] + red[2][1] + red[3][1];
        atomicAdd(&out[(kidx * 64 + d) * 2 + 0], -fr);
        atomicAdd(&out[(kidx * 64 + d) * 2 + 1], -fi);
    }
}

extern "C" void kernel_launch(void* const* d_in, const int* in_sizes, int n_in,
                              void* d_out, int out_size, void* d_ws, size_t ws_size,
                              hipStream_t stream) {
    const float* V   = (const float*)d_in[0];
    const float* obs = (const float*)d_in[1];
    const float* pts = (const float*)d_in[2];
    const float* w   = (const float*)d_in[3];
    float* ws  = (float*)d_ws;
    float* out = (float*)d_out;

    // d_out is re-poisoned before every call: zero it (far_k accumulates)
    hipMemsetAsync(out, 0, (size_t)out_size * 4, stream);

    init_k<<<64, 64, 0, stream>>>(V, pts, w, ws);
    if (ws_size >= WS_NEED_PART) {
        for (int it = 0; it < 5; it++) {
            matvec_k<NCHUNK, true><<<dim3(NCHUNK, 8), 256, 0, stream>>>(
                ws, (f2*)(ws + OFF_PART), ws + OFF_YR, ws + OFF_YI);
            reduce_update_k<NCHUNK><<<512, 256, 0, stream>>>(ws);
        }
    } else {
        for (int it = 0; it < 5; it++) {
            matvec_k<64, false><<<dim3(64, 8), 256, 0, stream>>>(
                ws, (f2*)(ws + OFF_PART), ws + OFF_YR, ws + OFF_YI);
            update_fallback_k<<<16, 256, 0, stream>>>(ws);
        }
    }
    far_k<<<512, 256, 0, stream>>>(obs, ws, out);
}

// Round 6
// 206.533 us; speedup vs baseline: 1.0674x; 1.0115x over previous
//
#include <hip/hip_runtime.h>

// Born-series scattering, M=4096 pts, 4 wavenumbers, 5 Born iterations,
// 64 obs dirs.
// R4: bit-faithful D^2 (Gram rounding sequence) -> absmax 0.0.
// R5-R8: atomics eliminated; fused chunk-reduce.
// R9-R15: scheduling/residency probes neutral (incl. 2x residency -> not
//   wave-starved).
// R16: 219.8us. R17: reduce butterfly + init regrid (215.4us).
// R18: hand-rolled persistent barrier -> HSA abort. R19: cooperative fusion
//   neutral (215.2us) -> launch gaps not the cost. R20: G-cache neutral ->
//   not trans-bound. R21: packed f32 (v_pk_*) -6.5us only (208.9us).
// R22: MARSHAL-FREE LAYOUT. v_pk ops need aligned VGPR pairs; the old
//   ACC_UPD built ri={ar[n],ai[n]} from two separate float4 planes plus a
//   negate/swap sw and splats -> ~25-30 marshal movs per column, likely
//   ~half the real issue count (explains R21's tiny gain). Colpack now
//   stores {ar,ai} interleaved (cp[4+2n],cp[5+2n]) so ri_n is a direct
//   aligned f2 load-slice and sw folds into VOP3P modifiers. Same values,
//   same op sequences -> absmax 0.0. Also: init_k regrid 4k->16k threads
//   (one (i,n)/thread), and init_k zeroes out[] (drops memset dispatch).
//
// ws layout (floats):
//   colpack[M][12]: x,y,z,r2, {ar,ai}[4] interleaved  (a = C*vw*psi per k)
//   cvw[M]; p0r[4][M], p0i[4][M]; yr[4][M], yi[4][M] (fallback)
//   part[C][4][M] of float2                           (partials, 16MB)

#define MM 4096
#define NK 4
#define CGREEN 0.07957747154594767f   // 1/(4*pi)
#define INV2PI 0.15915494309189535f   // 1/(2*pi)

#define OFF_VW   49152
#define OFF_P0R  53248
#define OFF_P0I  69632
#define OFF_YR   86016
#define OFF_YI   102400
#define OFF_PART 118784
#define NCHUNK 128
#define PART_FLOATS (NCHUNK * 8 * MM)
#define WS_NEED_PART ((size_t)(OFF_PART + PART_FLOATS) * 4)

typedef float f2 __attribute__((ext_vector_type(2)));

// Packed vector fma: v_pk_fma_f32 is bit-identical per component to
// v_fma_f32 -- packing only changes issue count, not rounding.
__device__ __forceinline__ f2 vfma(f2 a, f2 b, f2 c) {
#if __has_builtin(__builtin_elementwise_fma)
    return __builtin_elementwise_fma(a, b, c);
#else
    f2 r; r.x = fmaf(a.x, b.x, c.x); r.y = fmaf(a.y, b.y, c.y); return r;
#endif
}

__device__ __forceinline__ f2 vmax(f2 a, f2 b) {
#if __has_builtin(__builtin_elementwise_max)
    return __builtin_elementwise_max(a, b);
#else
    f2 r; r.x = fmaxf(a.x, b.x); r.y = fmaxf(a.y, b.y); return r;
#endif
}

__device__ __forceinline__ f2 splat(float v) { f2 r; r.x = v; r.y = v; return r; }

// One (point i, wavenumber n) init item. Interleaved a-slots: cp[4+2n]=ar,
// cp[5+2n]=ai -- same VALUES as the old planes, new positions.
__device__ __forceinline__ void init_item(int i, int n, const float* __restrict__ V,
                                          const float* __restrict__ pts,
                                          const float* __restrict__ w,
                                          float* __restrict__ ws, bool writeBase) {
#pragma clang fp contract(off)
    float x = pts[3 * i], y = pts[3 * i + 1], z = pts[3 * i + 2];
    float cvw = CGREEN * (V[i] * w[i]);
    float* cp = ws + i * 12;
    if (writeBase) {
        float xx = x * x, yy = y * y, zz = z * z;
        float r2 = (xx + yy) + zz;             // np rounding order
        cp[0] = x; cp[1] = y; cp[2] = z; cp[3] = r2;
        ws[OFF_VW + i] = cvw;
    }
    float kk = 0.5f * (float)(n + 1);
    float s, c;
    sincosf(kk * z, &s, &c);
    ws[OFF_P0R + n * MM + i] = c;
    ws[OFF_P0I + n * MM + i] = s;
    cp[4 + 2 * n] = cvw * c;
    cp[5 + 2 * n] = cvw * s;
}

// 16384 threads: one (i,n) item each (was 4096 threads / 64 waves -> pure
// latency exposure). Also zeroes out[] so the memset dispatch is dropped
// (far_k's atomic accumulation is order-commutative-exact).
__global__ __launch_bounds__(256) void init_k(const float* __restrict__ V,
                                              const float* __restrict__ pts,
                                              const float* __restrict__ w,
                                              float* __restrict__ ws,
                                              float* __restrict__ out,
                                              int out_n) {
    int t = blockIdx.x * 256 + threadIdx.x;    // [0, 16384)
    int i = t >> 2;
    int n = t & 3;
    init_item(i, n, V, pts, w, ws, n == 0);
    ws[OFF_YR + n * MM + i] = 0.0f;
    ws[OFF_YI + n * MM + i] = 0.0f;
    if (t < out_n) out[t] = 0.0f;
}

// One column vs TWO rows; all f2 math in vector form -> packed VOP3P.
// RIa = {ar0,ai0,ar1,ai1}, RIb = {ar2,ai2,ar3,ai3}: ri_n is an aligned
// f2 slice (no marshal); sw is a swizzle+neg (folds into modifiers).
__device__ __forceinline__ void body_col2(f2 rx, f2 ry, f2 rz, f2 rr2,
                                          int r0, int r1, int jg,
                                          float4 A, float4 RIa, float4 RIb,
                                          f2 acc0[4], f2 acc1[4]) {
    // ---- bit-faithful D^2, per-element rounding == reference sequence ----
    f2 d2;
    {
#pragma clang fp contract(off)
        f2 m = rx * splat(A.x);                            // rounded mul
        m = vfma(ry, splat(A.y), m);                       // k-order fma chain
        m = vfma(rz, splat(A.z), m);
        f2 r2s = rr2 + splat(A.w);                         // rounded add
        f2 twod = 2.0f * m;                                // exact
        d2 = r2s - twod;                                   // single rounded sub
    }
    d2 = vmax(d2, splat(1e-12f));
    // ---- fast-math (proven invisible in bucketed output) ----
    float ia = __builtin_amdgcn_rsqf(d2.x);
    float ib = __builtin_amdgcn_rsqf(d2.y);
    f2 invD = {ia, ib};
    f2 rev = d2 * invD * (0.5f * INV2PI);   // angle 0.5*D in revolutions
    float sca = (jg == r0) ? 0.0f : ia;
    float scb = (jg == r1) ? 0.0f : ib;
    f2 s1, c1;
    s1.x = __builtin_amdgcn_sinf(rev.x);    // raw v_sin: sin(2*pi*x)
    c1.x = __builtin_amdgcn_cosf(rev.x);
    s1.y = __builtin_amdgcn_sinf(rev.y);
    c1.y = __builtin_amdgcn_cosf(rev.y);
    f2 c2 = vfma(c1, c1, -(s1 * s1));
    f2 s2 = 2.0f * (c1 * s1);
    f2 c3 = vfma(c2, c1, -(s2 * s1));
    f2 s3 = vfma(s2, c1, c2 * s1);
    f2 c4 = vfma(c2, c2, -(s2 * s2));
    f2 s4 = 2.0f * (c2 * s2);
    const f2 vsca = splat(sca), vscb = splat(scb);
#define ACC_UPD(nn, CC, SS, RI)                                              \
    {                                                                        \
        f2 sw; sw.x = -RI.y; sw.y = RI.x;                                    \
        f2 t0 = splat(CC.x) * RI; t0 = vfma(splat(SS.x), sw, t0);            \
        acc0[nn] = vfma(vsca, t0, acc0[nn]);                                 \
        f2 t1 = splat(CC.y) * RI; t1 = vfma(splat(SS.y), sw, t1);            \
        acc1[nn] = vfma(vscb, t1, acc1[nn]);                                 \
    }
    f2 ri0; ri0.x = RIa.x; ri0.y = RIa.y;
    f2 ri1; ri1.x = RIa.z; ri1.y = RIa.w;
    f2 ri2; ri2.x = RIb.x; ri2.y = RIb.y;
    f2 ri3; ri3.x = RIb.z; ri3.y = RIb.w;
    ACC_UPD(0, c1, s1, ri0)
    ACC_UPD(1, c2, s2, ri1)
    ACC_UPD(2, c3, s3, ri2)
    ACC_UPD(3, c4, s4, ri3)
#undef ACC_UPD
}

// grid: (C chunks, 8 row-groups of 512); block 256; 2 rows/thread.
template <int C, bool USE_PART>
__global__ __launch_bounds__(256) void matvec_k(const float* __restrict__ cols,
                                                f2* __restrict__ part,
                                                float* __restrict__ yr,
                                                float* __restrict__ yi) {
    constexpr int TC = MM / C;                 // cols per block (32)
    const int chunk = blockIdx.x;
    const int rg = blockIdx.y;
    const int r0 = rg * 512 + threadIdx.x;
    const int r1 = r0 + 256;
    const float4 rowA = *(const float4*)&cols[r0 * 12];   // x,y,z,r2
    const float4 rowB = *(const float4*)&cols[r1 * 12];
    const f2 rx = {rowA.x, rowB.x}, ry = {rowA.y, rowB.y};
    const f2 rz = {rowA.z, rowB.z}, rr2 = {rowA.w, rowB.w};
    f2 acc0[4], acc1[4];
#pragma unroll
    for (int i = 0; i < 4; i++) {
        acc0[i].x = 0.0f; acc0[i].y = 0.0f;
        acc1[i].x = 0.0f; acc1[i].y = 0.0f;
    }
    const int jg0 = chunk * TC;
    const float* colbase = cols + (size_t)jg0 * 12;   // uniform across lanes
#pragma unroll 4
    for (int j = 0; j < TC; j++) {
        const float4* cp = (const float4*)(colbase + j * 12);
        float4 A = cp[0], RIa = cp[1], RIb = cp[2];
        body_col2(rx, ry, rz, rr2, r0, r1, jg0 + j, A, RIa, RIb, acc0, acc1);
    }
    if (USE_PART) {
#pragma unroll
        for (int n = 0; n < NK; n++) {
            part[(size_t)(chunk * 4 + n) * MM + r0] = acc0[n];
            part[(size_t)(chunk * 4 + n) * MM + r1] = acc1[n];
        }
    } else {
#pragma unroll
        for (int n = 0; n < NK; n++) {
            atomicAdd(&yr[n * MM + r0], acc0[n].x);
            atomicAdd(&yi[n * MM + r0], acc0[n].y);
            atomicAdd(&yr[n * MM + r1], acc1[n].x);
            atomicAdd(&yi[n * MM + r1], acc1[n].y);
        }
    }
}

// Fused chunk-reduction + psi update, 8 lanes per (n,row) (R17 structure).
// Writes the interleaved a-slots.
template <int C>
__global__ __launch_bounds__(256) void reduce_update_k(float* __restrict__ ws) {
    int t = blockIdx.x * 256 + threadIdx.x;        // [0, 131072)
    int u = t & 7;                                 // accumulator index
    int item = t >> 3;                             // [0, 16384) = (n,row)
    int row = item & (MM - 1);
    int n = item >> 12;                            // 0..3
    const f2* part2 = (const f2*)(ws + OFF_PART);
    f2 s; s.x = 0.0f; s.y = 0.0f;
#pragma unroll
    for (int j = 0; j < C / 8; j++) {
        int c = u + 8 * j;
        s += part2[(size_t)(c * 4 + n) * MM + row];
    }
    // exact combine tree via butterfly (a+b bitwise == b+a)
    s.x += __shfl_xor(s.x, 1); s.y += __shfl_xor(s.y, 1);
    s.x += __shfl_xor(s.x, 2); s.y += __shfl_xor(s.y, 2);
    s.x += __shfl_xor(s.x, 4); s.y += __shfl_xor(s.y, 4);
    if (u == 0) {
        float cvw = ws[OFF_VW + row];
        float pr = ws[OFF_P0R + n * MM + row] + s.x;
        float pi = ws[OFF_P0I + n * MM + row] + s.y;
        ws[row * 12 + 4 + 2 * n] = cvw * pr;
        ws[row * 12 + 5 + 2 * n] = cvw * pi;
    }
}

// atomic-fallback update (only used if ws too small for partials)
__global__ __launch_bounds__(256) void update_fallback_k(float* __restrict__ ws) {
    int i = blockIdx.x * 256 + threadIdx.x;
    float cvw = ws[OFF_VW + i];
#pragma unroll
    for (int n = 0; n < NK; n++) {
        float pr = ws[OFF_P0R + n * MM + i] + ws[OFF_YR + n * MM + i];
        float pi = ws[OFF_P0I + n * MM + i] + ws[OFF_YI + n * MM + i];
        ws[i * 12 + 4 + 2 * n] = cvw * pr;
        ws[i * 12 + 5 + 2 * n] = cvw * pi;
        ws[OFF_YR + n * MM + i] = 0.0f;
        ws[OFF_YI + n * MM + i] = 0.0f;
    }
}

// 512 blocks: (k, obs_dir, j-half). float4 loads from the colpack.
// Interleaved slots: AR={ar0,ai0,ar1,ai1}, AI={ar2,ai2,ar3,ai3}.
__global__ __launch_bounds__(256) void far_k(const float* __restrict__ obs,
                                             const float* __restrict__ ws,
                                             float* __restrict__ out) {
    int kidx = (blockIdx.x >> 1) >> 6;
    int d = (blockIdx.x >> 1) & 63;
    int half = blockIdx.x & 1;
    float kk = 0.5f * (float)(kidx + 1);
    float ox = obs[3 * d], oy = obs[3 * d + 1], oz = obs[3 * d + 2];
    float fr = 0.0f, fi = 0.0f;
    for (int j = half * 2048 + threadIdx.x; j < half * 2048 + 2048; j += 256) {
        const float4* c4 = (const float4*)(ws + j * 12);
        float4 P = c4[0], AR = c4[1], AI = c4[2];
        float q = fmaf(P.z, oz, fmaf(P.y, oy, P.x * ox));
        float ar, ai;
        switch (kidx) {
            case 0: ar = AR.x; ai = AR.y; break;
            case 1: ar = AR.z; ai = AR.w; break;
            case 2: ar = AI.x; ai = AI.y; break;
            default: ar = AI.z; ai = AI.w; break;
        }
        float s, co;
        __sincosf(kk * q, &s, &co);
        fr += fmaf(ar, co,  ai * s);
        fi += fmaf(ai, co, -ar * s);
    }
#pragma unroll
    for (int off = 32; off > 0; off >>= 1) {
        fr += __shfl_down(fr, off);
        fi += __shfl_down(fi, off);
    }
    __shared__ float red[4][2];
    int wave = threadIdx.x >> 6;
    if ((threadIdx.x & 63) == 0) { red[wave][0] = fr; red[wave][1] = fi; }
    __syncthreads();
    if (threadIdx.x == 0) {
        fr = red[0][0] + red[1][0] + red[2][0] + red[3][0];
        fi = red[0][1] + red[1][1] + red[2][1] + red[3][1];
        atomicAdd(&out[(kidx * 64 + d) * 2 + 0], -fr);
        atomicAdd(&out[(kidx * 64 + d) * 2 + 1], -fi);
    }
}

extern "C" void kernel_launch(void* const* d_in, const int* in_sizes, int n_in,
                              void* d_out, int out_size, void* d_ws, size_t ws_size,
                              hipStream_t stream) {
    const float* V   = (const float*)d_in[0];
    const float* obs = (const float*)d_in[1];
    const float* pts = (const float*)d_in[2];
    const float* w   = (const float*)d_in[3];
    float* ws  = (float*)d_ws;
    float* out = (float*)d_out;

    // out is zeroed inside init_k (d_out re-poisoned before every call).
    init_k<<<64, 256, 0, stream>>>(V, pts, w, ws, out, out_size);
    if (ws_size >= WS_NEED_PART) {
        for (int it = 0; it < 5; it++) {
            matvec_k<NCHUNK, true><<<dim3(NCHUNK, 8), 256, 0, stream>>>(
                ws, (f2*)(ws + OFF_PART), ws + OFF_YR, ws + OFF_YI);
            reduce_update_k<NCHUNK><<<512, 256, 0, stream>>>(ws);
        }
    } else {
        for (int it = 0; it < 5; it++) {
            matvec_k<64, false><<<dim3(64, 8), 256, 0, stream>>>(
                ws, (f2*)(ws + OFF_PART), ws + OFF_YR, ws + OFF_YI);
            update_fallback_k<<<16, 256, 0, stream>>>(ws);
        }
    }
    far_k<<<512, 256, 0, stream>>>(obs, ws, out);
}

// Round 7
// 206.517 us; speedup vs baseline: 1.0675x; 1.0001x over previous
//
#include <hip/hip_runtime.h>

// Born-series scattering, M=4096 pts, 4 wavenumbers, 5 Born iterations,
// 64 obs dirs.
// R4: bit-faithful D^2 (Gram rounding sequence) -> absmax 0.0.
// R5-R8: atomics eliminated; fused chunk-reduce.
// R9-R15: scheduling/residency probes neutral; 2x residency regressed.
// R16: 219.8. R17: reduce butterfly + init regrid (215.4).
// R18: persistent barrier -> abort. R19: coop fusion neutral (215.2).
// R20: G-cache neutral -> not trans-throughput-bound.
// R21: packed f32 -6.5 (208.9). R22: interleaved layout -2.4 (206.5).
// R23: DUAL-COLUMN PIPELINE. Utilization arithmetic: 712 cy per
//   wave-col-iter at 4 waves/SIMD = ~15% VALU issue utilization -> the
//   body is LATENCY-bound on its ~25-step dependent chain with ~no
//   cross-column overlap (compiler serializes the unroll-4 chains to meet
//   its occupancy register target). Fix: process 2 columns per step with
//   the two front-end chains manually interleaved in source (A/B
//   alternation), acc updates applied in exact j then j+1 order (bitwise
//   identical sum sequence). __launch_bounds__(256,4) pins the 128-VGPR /
//   4-wave budget; 2-chain working set ~100 VGPR fits. 8 concurrent
//   chains/SIMD vs ~4.
//
// ws layout (floats):
//   colpack[M][12]: x,y,z,r2, {ar,ai}[4] interleaved  (a = C*vw*psi per k)
//   cvw[M]; p0r[4][M], p0i[4][M]; yr[4][M], yi[4][M] (fallback)
//   part[C][4][M] of float2                           (partials, 16MB)

#define MM 4096
#define NK 4
#define CGREEN 0.07957747154594767f   // 1/(4*pi)
#define INV2PI 0.15915494309189535f   // 1/(2*pi)

#define OFF_VW   49152
#define OFF_P0R  53248
#define OFF_P0I  69632
#define OFF_YR   86016
#define OFF_YI   102400
#define OFF_PART 118784
#define NCHUNK 128
#define PART_FLOATS (NCHUNK * 8 * MM)
#define WS_NEED_PART ((size_t)(OFF_PART + PART_FLOATS) * 4)

typedef float f2 __attribute__((ext_vector_type(2)));

__device__ __forceinline__ f2 vfma(f2 a, f2 b, f2 c) {
#if __has_builtin(__builtin_elementwise_fma)
    return __builtin_elementwise_fma(a, b, c);
#else
    f2 r; r.x = fmaf(a.x, b.x, c.x); r.y = fmaf(a.y, b.y, c.y); return r;
#endif
}

__device__ __forceinline__ f2 vmax(f2 a, f2 b) {
#if __has_builtin(__builtin_elementwise_max)
    return __builtin_elementwise_max(a, b);
#else
    f2 r; r.x = fmaxf(a.x, b.x); r.y = fmaxf(a.y, b.y); return r;
#endif
}

__device__ __forceinline__ f2 splat(float v) { f2 r; r.x = v; r.y = v; return r; }

// One (point i, wavenumber n) init item. Interleaved a-slots: cp[4+2n]=ar,
// cp[5+2n]=ai.
__device__ __forceinline__ void init_item(int i, int n, const float* __restrict__ V,
                                          const float* __restrict__ pts,
                                          const float* __restrict__ w,
                                          float* __restrict__ ws, bool writeBase) {
#pragma clang fp contract(off)
    float x = pts[3 * i], y = pts[3 * i + 1], z = pts[3 * i + 2];
    float cvw = CGREEN * (V[i] * w[i]);
    float* cp = ws + i * 12;
    if (writeBase) {
        float xx = x * x, yy = y * y, zz = z * z;
        float r2 = (xx + yy) + zz;             // np rounding order
        cp[0] = x; cp[1] = y; cp[2] = z; cp[3] = r2;
        ws[OFF_VW + i] = cvw;
    }
    float kk = 0.5f * (float)(n + 1);
    float s, c;
    sincosf(kk * z, &s, &c);
    ws[OFF_P0R + n * MM + i] = c;
    ws[OFF_P0I + n * MM + i] = s;
    cp[4 + 2 * n] = cvw * c;
    cp[5 + 2 * n] = cvw * s;
}

// 16384 threads: one (i,n) item each; zeroes out[] (no memset dispatch).
__global__ __launch_bounds__(256) void init_k(const float* __restrict__ V,
                                              const float* __restrict__ pts,
                                              const float* __restrict__ w,
                                              float* __restrict__ ws,
                                              float* __restrict__ out,
                                              int out_n) {
    int t = blockIdx.x * 256 + threadIdx.x;    // [0, 16384)
    int i = t >> 2;
    int n = t & 3;
    init_item(i, n, V, pts, w, ws, n == 0);
    ws[OFF_YR + n * MM + i] = 0.0f;
    ws[OFF_YI + n * MM + i] = 0.0f;
    if (t < out_n) out[t] = 0.0f;
}

// Front-end chain results for one column vs the row pair.
struct FE {
    f2 c1, s1, c2, s2, c3, s3, c4, s4;
    f2 vsca, vscb;
};

// Apply one column's 8 accumulator updates (exact same op sequence as R22).
__device__ __forceinline__ void acc_apply(const FE& f, float4 RIa, float4 RIb,
                                          f2 acc0[4], f2 acc1[4]) {
#define ACC_UPD(nn, CC, SS, RI)                                              \
    {                                                                        \
        f2 sw; sw.x = -RI.y; sw.y = RI.x;                                    \
        f2 t0 = splat(CC.x) * RI; t0 = vfma(splat(SS.x), sw, t0);            \
        acc0[nn] = vfma(f.vsca, t0, acc0[nn]);                               \
        f2 t1 = splat(CC.y) * RI; t1 = vfma(splat(SS.y), sw, t1);            \
        acc1[nn] = vfma(f.vscb, t1, acc1[nn]);                               \
    }
    f2 ri0; ri0.x = RIa.x; ri0.y = RIa.y;
    f2 ri1; ri1.x = RIa.z; ri1.y = RIa.w;
    f2 ri2; ri2.x = RIb.x; ri2.y = RIb.y;
    f2 ri3; ri3.x = RIb.z; ri3.y = RIb.w;
    ACC_UPD(0, f.c1, f.s1, ri0)
    ACC_UPD(1, f.c2, f.s2, ri1)
    ACC_UPD(2, f.c3, f.s3, ri2)
    ACC_UPD(3, f.c4, f.s4, ri3)
#undef ACC_UPD
}

// TWO columns vs TWO rows: front-end chains A/B manually interleaved so
// both dependent chains are in flight; acc updates strictly col jA then
// col jB (identical per-accumulator add order to the serial loop).
__device__ __forceinline__ void body_col_pair(f2 rx, f2 ry, f2 rz, f2 rr2,
                                              int r0, int r1,
                                              int jgA, float4 Aa,
                                              int jgB, float4 Ab,
                                              float4 RIaA, float4 RIbA,
                                              float4 RIaB, float4 RIbB,
                                              f2 acc0[4], f2 acc1[4]) {
    FE fa, fb;
    // ---- D^2, bit-faithful, two chains interleaved ----
    f2 d2a, d2b;
    {
#pragma clang fp contract(off)
        f2 ma = rx * splat(Aa.x);
        f2 mb = rx * splat(Ab.x);
        ma = vfma(ry, splat(Aa.y), ma);
        mb = vfma(ry, splat(Ab.y), mb);
        ma = vfma(rz, splat(Aa.z), ma);
        mb = vfma(rz, splat(Ab.z), mb);
        f2 r2sa = rr2 + splat(Aa.w);
        f2 r2sb = rr2 + splat(Ab.w);
        f2 twoda = 2.0f * ma;
        f2 twodb = 2.0f * mb;
        d2a = r2sa - twoda;
        d2b = r2sb - twodb;
    }
    d2a = vmax(d2a, splat(1e-12f));
    d2b = vmax(d2b, splat(1e-12f));
    // ---- fast-math trans, interleaved ----
    float iaA = __builtin_amdgcn_rsqf(d2a.x);
    float iaB = __builtin_amdgcn_rsqf(d2b.x);
    float ibA = __builtin_amdgcn_rsqf(d2a.y);
    float ibB = __builtin_amdgcn_rsqf(d2b.y);
    f2 invDa = {iaA, ibA};
    f2 invDb = {iaB, ibB};
    f2 reva = d2a * invDa * (0.5f * INV2PI);
    f2 revb = d2b * invDb * (0.5f * INV2PI);
    fa.vsca = splat((jgA == r0) ? 0.0f : iaA);
    fb.vsca = splat((jgB == r0) ? 0.0f : iaB);
    fa.vscb = splat((jgA == r1) ? 0.0f : ibA);
    fb.vscb = splat((jgB == r1) ? 0.0f : ibB);
    fa.s1.x = __builtin_amdgcn_sinf(reva.x);
    fb.s1.x = __builtin_amdgcn_sinf(revb.x);
    fa.c1.x = __builtin_amdgcn_cosf(reva.x);
    fb.c1.x = __builtin_amdgcn_cosf(revb.x);
    fa.s1.y = __builtin_amdgcn_sinf(reva.y);
    fb.s1.y = __builtin_amdgcn_sinf(revb.y);
    fa.c1.y = __builtin_amdgcn_cosf(reva.y);
    fb.c1.y = __builtin_amdgcn_cosf(revb.y);
    // ---- Chebyshev recurrence, interleaved ----
    fa.c2 = vfma(fa.c1, fa.c1, -(fa.s1 * fa.s1));
    fb.c2 = vfma(fb.c1, fb.c1, -(fb.s1 * fb.s1));
    fa.s2 = 2.0f * (fa.c1 * fa.s1);
    fb.s2 = 2.0f * (fb.c1 * fb.s1);
    fa.c3 = vfma(fa.c2, fa.c1, -(fa.s2 * fa.s1));
    fb.c3 = vfma(fb.c2, fb.c1, -(fb.s2 * fb.s1));
    fa.s3 = vfma(fa.s2, fa.c1, fa.c2 * fa.s1);
    fb.s3 = vfma(fb.s2, fb.c1, fb.c2 * fb.s1);
    fa.c4 = vfma(fa.c2, fa.c2, -(fa.s2 * fa.s2));
    fb.c4 = vfma(fb.c2, fb.c2, -(fb.s2 * fb.s2));
    fa.s4 = 2.0f * (fa.c2 * fa.s2);
    fb.s4 = 2.0f * (fb.c2 * fb.s2);
    // ---- accumulate: col jA fully, THEN col jB (exact j order) ----
    acc_apply(fa, RIaA, RIbA, acc0, acc1);
    acc_apply(fb, RIaB, RIbB, acc0, acc1);
}

// grid: (C chunks, 8 row-groups of 512); block 256; 2 rows x 2 cols/thread.
template <int C, bool USE_PART>
__global__ __launch_bounds__(256, 4) void matvec_k(const float* __restrict__ cols,
                                                   f2* __restrict__ part,
                                                   float* __restrict__ yr,
                                                   float* __restrict__ yi) {
    constexpr int TC = MM / C;                 // cols per block (32)
    const int chunk = blockIdx.x;
    const int rg = blockIdx.y;
    const int r0 = rg * 512 + threadIdx.x;
    const int r1 = r0 + 256;
    const float4 rowA = *(const float4*)&cols[r0 * 12];   // x,y,z,r2
    const float4 rowB = *(const float4*)&cols[r1 * 12];
    const f2 rx = {rowA.x, rowB.x}, ry = {rowA.y, rowB.y};
    const f2 rz = {rowA.z, rowB.z}, rr2 = {rowA.w, rowB.w};
    f2 acc0[4], acc1[4];
#pragma unroll
    for (int i = 0; i < 4; i++) {
        acc0[i].x = 0.0f; acc0[i].y = 0.0f;
        acc1[i].x = 0.0f; acc1[i].y = 0.0f;
    }
    const int jg0 = chunk * TC;
    const float* colbase = cols + (size_t)jg0 * 12;   // uniform across lanes
#pragma unroll 2
    for (int j = 0; j < TC; j += 2) {
        const float4* cpA = (const float4*)(colbase + j * 12);
        const float4* cpB = (const float4*)(colbase + (j + 1) * 12);
        float4 Aa = cpA[0], RIaA = cpA[1], RIbA = cpA[2];
        float4 Ab = cpB[0], RIaB = cpB[1], RIbB = cpB[2];
        body_col_pair(rx, ry, rz, rr2, r0, r1,
                      jg0 + j, Aa, jg0 + j + 1, Ab,
                      RIaA, RIbA, RIaB, RIbB, acc0, acc1);
    }
    if (USE_PART) {
#pragma unroll
        for (int n = 0; n < NK; n++) {
            part[(size_t)(chunk * 4 + n) * MM + r0] = acc0[n];
            part[(size_t)(chunk * 4 + n) * MM + r1] = acc1[n];
        }
    } else {
#pragma unroll
        for (int n = 0; n < NK; n++) {
            atomicAdd(&yr[n * MM + r0], acc0[n].x);
            atomicAdd(&yi[n * MM + r0], acc0[n].y);
            atomicAdd(&yr[n * MM + r1], acc1[n].x);
            atomicAdd(&yi[n * MM + r1], acc1[n].y);
        }
    }
}

// Fused chunk-reduction + psi update, 8 lanes per (n,row) (R17 structure).
template <int C>
__global__ __launch_bounds__(256) void reduce_update_k(float* __restrict__ ws) {
    int t = blockIdx.x * 256 + threadIdx.x;        // [0, 131072)
    int u = t & 7;                                 // accumulator index
    int item = t >> 3;                             // [0, 16384) = (n,row)
    int row = item & (MM - 1);
    int n = item >> 12;                            // 0..3
    const f2* part2 = (const f2*)(ws + OFF_PART);
    f2 s; s.x = 0.0f; s.y = 0.0f;
#pragma unroll
    for (int j = 0; j < C / 8; j++) {
        int c = u + 8 * j;
        s += part2[(size_t)(c * 4 + n) * MM + row];
    }
    // exact combine tree via butterfly (a+b bitwise == b+a)
    s.x += __shfl_xor(s.x, 1); s.y += __shfl_xor(s.y, 1);
    s.x += __shfl_xor(s.x, 2); s.y += __shfl_xor(s.y, 2);
    s.x += __shfl_xor(s.x, 4); s.y += __shfl_xor(s.y, 4);
    if (u == 0) {
        float cvw = ws[OFF_VW + row];
        float pr = ws[OFF_P0R + n * MM + row] + s.x;
        float pi = ws[OFF_P0I + n * MM + row] + s.y;
        ws[row * 12 + 4 + 2 * n] = cvw * pr;
        ws[row * 12 + 5 + 2 * n] = cvw * pi;
    }
}

// atomic-fallback update (only used if ws too small for partials)
__global__ __launch_bounds__(256) void update_fallback_k(float* __restrict__ ws) {
    int i = blockIdx.x * 256 + threadIdx.x;
    float cvw = ws[OFF_VW + i];
#pragma unroll
    for (int n = 0; n < NK; n++) {
        float pr = ws[OFF_P0R + n * MM + i] + ws[OFF_YR + n * MM + i];
        float pi = ws[OFF_P0I + n * MM + i] + ws[OFF_YI + n * MM + i];
        ws[i * 12 + 4 + 2 * n] = cvw * pr;
        ws[i * 12 + 5 + 2 * n] = cvw * pi;
        ws[OFF_YR + n * MM + i] = 0.0f;
        ws[OFF_YI + n * MM + i] = 0.0f;
    }
}

// 512 blocks: (k, obs_dir, j-half). Interleaved slots:
// AR={ar0,ai0,ar1,ai1}, AI={ar2,ai2,ar3,ai3}.
__global__ __launch_bounds__(256) void far_k(const float* __restrict__ obs,
                                             const float* __restrict__ ws,
                                             float* __restrict__ out) {
    int kidx = (blockIdx.x >> 1) >> 6;
    int d = (blockIdx.x >> 1) & 63;
    int half = blockIdx.x & 1;
    float kk = 0.5f * (float)(kidx + 1);
    float ox = obs[3 * d], oy = obs[3 * d + 1], oz = obs[3 * d + 2];
    float fr = 0.0f, fi = 0.0f;
    for (int j = half * 2048 + threadIdx.x; j < half * 2048 + 2048; j += 256) {
        const float4* c4 = (const float4*)(ws + j * 12);
        float4 P = c4[0], AR = c4[1], AI = c4[2];
        float q = fmaf(P.z, oz, fmaf(P.y, oy, P.x * ox));
        float ar, ai;
        switch (kidx) {
            case 0: ar = AR.x; ai = AR.y; break;
            case 1: ar = AR.z; ai = AR.w; break;
            case 2: ar = AI.x; ai = AI.y; break;
            default: ar = AI.z; ai = AI.w; break;
        }
        float s, co;
        __sincosf(kk * q, &s, &co);
        fr += fmaf(ar, co,  ai * s);
        fi += fmaf(ai, co, -ar * s);
    }
#pragma unroll
    for (int off = 32; off > 0; off >>= 1) {
        fr += __shfl_down(fr, off);
        fi += __shfl_down(fi, off);
    }
    __shared__ float red[4][2];
    int wave = threadIdx.x >> 6;
    if ((threadIdx.x & 63) == 0) { red[wave][0] = fr; red[wave][1] = fi; }
    __syncthreads();
    if (threadIdx.x == 0) {
        fr = red[0][0] + red[1][0] + red[2][0] + red[3][0];
        fi = red[0][1] + red[1][1] + red[2][1] + red[3][1];
        atomicAdd(&out[(kidx * 64 + d) * 2 + 0], -fr);
        atomicAdd(&out[(kidx * 64 + d) * 2 + 1], -fi);
    }
}

extern "C" void kernel_launch(void* const* d_in, const int* in_sizes, int n_in,
                              void* d_out, int out_size, void* d_ws, size_t ws_size,
                              hipStream_t stream) {
    const float* V   = (const float*)d_in[0];
    const float* obs = (const float*)d_in[1];
    const float* pts = (const float*)d_in[2];
    const float* w   = (const float*)d_in[3];
    float* ws  = (float*)d_ws;
    float* out = (float*)d_out;

    // out is zeroed inside init_k (d_out re-poisoned before every call).
    init_k<<<64, 256, 0, stream>>>(V, pts, w, ws, out, out_size);
    if (ws_size >= WS_NEED_PART) {
        for (int it = 0; it < 5; it++) {
            matvec_k<NCHUNK, true><<<dim3(NCHUNK, 8), 256, 0, stream>>>(
                ws, (f2*)(ws + OFF_PART), ws + OFF_YR, ws + OFF_YI);
            reduce_update_k<NCHUNK><<<512, 256, 0, stream>>>(ws);
        }
    } else {
        for (int it = 0; it < 5; it++) {
            matvec_k<64, false><<<dim3(64, 8), 256, 0, stream>>>(
                ws, (f2*)(ws + OFF_PART), ws + OFF_YR, ws + OFF_YI);
            update_fallback_k<<<16, 256, 0, stream>>>(ws);
        }
    }
    far_k<<<512, 256, 0, stream>>>(obs, ws, out);
}

// Round 9
// 206.403 us; speedup vs baseline: 1.0681x; 1.0006x over previous
//
#include <hip/hip_runtime.h>

// Born-series scattering, M=4096 pts, 4 wavenumbers, 5 Born iterations,
// 64 obs dirs.
// R4: bit-faithful D^2 (Gram rounding sequence) -> absmax 0.0.
// R5-R8: atomics eliminated; fused chunk-reduce.
// R9-R15: scheduling/residency probes neutral; 8-wave residency regressed.
// R16: 219.8. R17: reduce butterfly + init regrid (215.4).
// R18: persistent barrier -> abort. R19: coop fusion neutral -> launch gaps
//   not the cost. R20: G-cache neutral -> not trans-throughput-bound.
// R21: packed f32 -6.5 (208.9). R22: interleaved {ar,ai} layout -2.4 (206.5).
// R23: dual-col ILP @ 128-VGPR cap -> EXACTLY neutral. Reading: the 2-col
//   working set (~150 VGPR) cannot fit 128 -> spill canceled the ILP gain
//   (or compiler already had it). Either way the ILP probes so far were
//   register-starved.
// R24: QUAD-COLUMN ILP AT LOW OCCUPANCY. __launch_bounds__(256,2): <=256
//   VGPR, 2 waves/SIMD. 4 columns' front-end chains interleaved stage-by-
//   stage (fully-unrolled constant-index loops -> registers, rule #20), acc
//   updates applied strictly in ascending j order -> every op sequence is
//   R22's verbatim -> absmax 0.0. 2 waves x 4 chains = 8 independent
//   dependent-chains per SIMD, WITH registers to hold them (~170 VGPR).
//   (R24 first submit died on a stray statement; logic unchanged here.)
//
// ws layout (floats):
//   colpack[M][12]: x,y,z,r2, {ar,ai}[4] interleaved  (a = C*vw*psi per k)
//   cvw[M]; p0r[4][M], p0i[4][M]; yr[4][M], yi[4][M] (fallback)
//   part[C][4][M] of float2                           (partials, 16MB)

#define MM 4096
#define NK 4
#define CGREEN 0.07957747154594767f   // 1/(4*pi)
#define INV2PI 0.15915494309189535f   // 1/(2*pi)

#define OFF_VW   49152
#define OFF_P0R  53248
#define OFF_P0I  69632
#define OFF_YR   86016
#define OFF_YI   102400
#define OFF_PART 118784
#define NCHUNK 128
#define PART_FLOATS (NCHUNK * 8 * MM)
#define WS_NEED_PART ((size_t)(OFF_PART + PART_FLOATS) * 4)

typedef float f2 __attribute__((ext_vector_type(2)));

__device__ __forceinline__ f2 vfma(f2 a, f2 b, f2 c) {
#if __has_builtin(__builtin_elementwise_fma)
    return __builtin_elementwise_fma(a, b, c);
#else
    f2 r; r.x = fmaf(a.x, b.x, c.x); r.y = fmaf(a.y, b.y, c.y); return r;
#endif
}

__device__ __forceinline__ f2 vmax2(f2 a, f2 b) {
#if __has_builtin(__builtin_elementwise_max)
    return __builtin_elementwise_max(a, b);
#else
    f2 r; r.x = fmaxf(a.x, b.x); r.y = fmaxf(a.y, b.y); return r;
#endif
}

__device__ __forceinline__ f2 splat(float v) { f2 r; r.x = v; r.y = v; return r; }

// One (point i, wavenumber n) init item. Interleaved a-slots: cp[4+2n]=ar,
// cp[5+2n]=ai.
__device__ __forceinline__ void init_item(int i, int n, const float* __restrict__ V,
                                          const float* __restrict__ pts,
                                          const float* __restrict__ w,
                                          float* __restrict__ ws, bool writeBase) {
#pragma clang fp contract(off)
    float x = pts[3 * i], y = pts[3 * i + 1], z = pts[3 * i + 2];
    float cvw = CGREEN * (V[i] * w[i]);
    float* cp = ws + i * 12;
    if (writeBase) {
        float xx = x * x, yy = y * y, zz = z * z;
        float r2 = (xx + yy) + zz;             // np rounding order
        cp[0] = x; cp[1] = y; cp[2] = z; cp[3] = r2;
        ws[OFF_VW + i] = cvw;
    }
    float kk = 0.5f * (float)(n + 1);
    float s, c;
    sincosf(kk * z, &s, &c);
    ws[OFF_P0R + n * MM + i] = c;
    ws[OFF_P0I + n * MM + i] = s;
    cp[4 + 2 * n] = cvw * c;
    cp[5 + 2 * n] = cvw * s;
}

// 16384 threads: one (i,n) item each; zeroes out[] (no memset dispatch).
__global__ __launch_bounds__(256) void init_k(const float* __restrict__ V,
                                              const float* __restrict__ pts,
                                              const float* __restrict__ w,
                                              float* __restrict__ ws,
                                              float* __restrict__ out,
                                              int out_n) {
    int t = blockIdx.x * 256 + threadIdx.x;    // [0, 16384)
    int i = t >> 2;
    int n = t & 3;
    init_item(i, n, V, pts, w, ws, n == 0);
    ws[OFF_YR + n * MM + i] = 0.0f;
    ws[OFF_YI + n * MM + i] = 0.0f;
    if (t < out_n) out[t] = 0.0f;
}

// Front-end chain results for one column vs the row pair.
struct FE {
    f2 c1, s1, c2, s2, c3, s3, c4, s4;
    f2 vsca, vscb;
};

// Apply one column's 8 accumulator updates (exact R22 op sequence).
__device__ __forceinline__ void acc_apply(const FE& f, float4 RIa, float4 RIb,
                                          f2 acc0[4], f2 acc1[4]) {
#define ACC_UPD(nn, CC, SS, RI)                                              \
    {                                                                        \
        f2 sw; sw.x = -RI.y; sw.y = RI.x;                                    \
        f2 t0 = splat(CC.x) * RI; t0 = vfma(splat(SS.x), sw, t0);            \
        acc0[nn] = vfma(f.vsca, t0, acc0[nn]);                               \
        f2 t1 = splat(CC.y) * RI; t1 = vfma(splat(SS.y), sw, t1);            \
        acc1[nn] = vfma(f.vscb, t1, acc1[nn]);                               \
    }
    f2 ri0; ri0.x = RIa.x; ri0.y = RIa.y;
    f2 ri1; ri1.x = RIa.z; ri1.y = RIa.w;
    f2 ri2; ri2.x = RIb.x; ri2.y = RIb.y;
    f2 ri3; ri3.x = RIb.z; ri3.y = RIb.w;
    ACC_UPD(0, f.c1, f.s1, ri0)
    ACC_UPD(1, f.c2, f.s2, ri1)
    ACC_UPD(2, f.c3, f.s3, ri2)
    ACC_UPD(3, f.c4, f.s4, ri3)
#undef ACC_UPD
}

// grid: (C chunks, 8 row-groups of 512); block 256; 2 rows x 4 cols/step.
// launch_bounds(256,2): <=256 VGPR, 2 waves/SIMD -- room for 4 chains.
template <int C, bool USE_PART>
__global__ __launch_bounds__(256, 2) void matvec_k(const float* __restrict__ cols,
                                                   f2* __restrict__ part,
                                                   float* __restrict__ yr,
                                                   float* __restrict__ yi) {
    constexpr int TC = MM / C;                 // cols per block (32)
    const int chunk = blockIdx.x;
    const int rg = blockIdx.y;
    const int r0 = rg * 512 + threadIdx.x;
    const int r1 = r0 + 256;
    const float4 rowA = *(const float4*)&cols[r0 * 12];   // x,y,z,r2
    const float4 rowB = *(const float4*)&cols[r1 * 12];
    const f2 rx = {rowA.x, rowB.x}, ry = {rowA.y, rowB.y};
    const f2 rz = {rowA.z, rowB.z}, rr2 = {rowA.w, rowB.w};
    f2 acc0[4], acc1[4];
#pragma unroll
    for (int i = 0; i < 4; i++) {
        acc0[i].x = 0.0f; acc0[i].y = 0.0f;
        acc1[i].x = 0.0f; acc1[i].y = 0.0f;
    }
    const int jg0 = chunk * TC;
    const float* colbase = cols + (size_t)jg0 * 12;   // uniform across lanes

    for (int j = 0; j < TC; j += 4) {
        // ---- load 4 columns (constant-index unroll -> registers) ----
        float4 Ax[4], RIax[4], RIbx[4];
#pragma unroll
        for (int q = 0; q < 4; q++) {
            const float4* cp = (const float4*)(colbase + (j + q) * 12);
            Ax[q] = cp[0]; RIax[q] = cp[1]; RIbx[q] = cp[2];
        }
        FE f[4];
        f2 d2[4];
        // ---- D^2 stage, 4 chains interleaved; bit-faithful sequence ----
        {
#pragma clang fp contract(off)
            f2 m[4], r2s[4], twod[4];
#pragma unroll
            for (int q = 0; q < 4; q++) m[q] = rx * splat(Ax[q].x);
#pragma unroll
            for (int q = 0; q < 4; q++) m[q] = vfma(ry, splat(Ax[q].y), m[q]);
#pragma unroll
            for (int q = 0; q < 4; q++) m[q] = vfma(rz, splat(Ax[q].z), m[q]);
#pragma unroll
            for (int q = 0; q < 4; q++) r2s[q] = rr2 + splat(Ax[q].w);
#pragma unroll
            for (int q = 0; q < 4; q++) twod[q] = 2.0f * m[q];
#pragma unroll
            for (int q = 0; q < 4; q++) d2[q] = r2s[q] - twod[q];
        }
#pragma unroll
        for (int q = 0; q < 4; q++) d2[q] = vmax2(d2[q], splat(1e-12f));
        // ---- rsq / rev / sc stage ----
        float ia[4], ib[4];
#pragma unroll
        for (int q = 0; q < 4; q++) ia[q] = __builtin_amdgcn_rsqf(d2[q].x);
#pragma unroll
        for (int q = 0; q < 4; q++) ib[q] = __builtin_amdgcn_rsqf(d2[q].y);
        f2 rev[4];
#pragma unroll
        for (int q = 0; q < 4; q++) {
            f2 invD = {ia[q], ib[q]};
            rev[q] = d2[q] * invD * (0.5f * INV2PI);
        }
#pragma unroll
        for (int q = 0; q < 4; q++) {
            int jg = jg0 + j + q;
            f[q].vsca = splat((jg == r0) ? 0.0f : ia[q]);
            f[q].vscb = splat((jg == r1) ? 0.0f : ib[q]);
        }
        // ---- sincos stage ----
#pragma unroll
        for (int q = 0; q < 4; q++) f[q].s1.x = __builtin_amdgcn_sinf(rev[q].x);
#pragma unroll
        for (int q = 0; q < 4; q++) f[q].c1.x = __builtin_amdgcn_cosf(rev[q].x);
#pragma unroll
        for (int q = 0; q < 4; q++) f[q].s1.y = __builtin_amdgcn_sinf(rev[q].y);
#pragma unroll
        for (int q = 0; q < 4; q++) f[q].c1.y = __builtin_amdgcn_cosf(rev[q].y);
        // ---- Chebyshev recurrence stage ----
#pragma unroll
        for (int q = 0; q < 4; q++) {
            f[q].c2 = vfma(f[q].c1, f[q].c1, -(f[q].s1 * f[q].s1));
            f[q].s2 = 2.0f * (f[q].c1 * f[q].s1);
            f[q].c3 = vfma(f[q].c2, f[q].c1, -(f[q].s2 * f[q].s1));
            f[q].s3 = vfma(f[q].s2, f[q].c1, f[q].c2 * f[q].s1);
            f[q].c4 = vfma(f[q].c2, f[q].c2, -(f[q].s2 * f[q].s2));
            f[q].s4 = 2.0f * (f[q].c2 * f[q].s2);
        }
        // ---- accumulate strictly in ascending j order (bit-exact) ----
#pragma unroll
        for (int q = 0; q < 4; q++)
            acc_apply(f[q], RIax[q], RIbx[q], acc0, acc1);
    }
    if (USE_PART) {
#pragma unroll
        for (int n = 0; n < NK; n++) {
            part[(size_t)(chunk * 4 + n) * MM + r0] = acc0[n];
            part[(size_t)(chunk * 4 + n) * MM + r1] = acc1[n];
        }
    } else {
#pragma unroll
        for (int n = 0; n < NK; n++) {
            atomicAdd(&yr[n * MM + r0], acc0[n].x);
            atomicAdd(&yi[n * MM + r0], acc0[n].y);
            atomicAdd(&yr[n * MM + r1], acc1[n].x);
            atomicAdd(&yi[n * MM + r1], acc1[n].y);
        }
    }
}

// Fused chunk-reduction + psi update, 8 lanes per (n,row) (R17 structure).
template <int C>
__global__ __launch_bounds__(256) void reduce_update_k(float* __restrict__ ws) {
    int t = blockIdx.x * 256 + threadIdx.x;        // [0, 131072)
    int u = t & 7;                                 // accumulator index
    int item = t >> 3;                             // [0, 16384) = (n,row)
    int row = item & (MM - 1);
    int n = item >> 12;                            // 0..3
    const f2* part2 = (const f2*)(ws + OFF_PART);
    f2 s; s.x = 0.0f; s.y = 0.0f;
#pragma unroll
    for (int j = 0; j < C / 8; j++) {
        int c = u + 8 * j;
        s += part2[(size_t)(c * 4 + n) * MM + row];
    }
    // exact combine tree via butterfly (a+b bitwise == b+a)
    s.x += __shfl_xor(s.x, 1); s.y += __shfl_xor(s.y, 1);
    s.x += __shfl_xor(s.x, 2); s.y += __shfl_xor(s.y, 2);
    s.x += __shfl_xor(s.x, 4); s.y += __shfl_xor(s.y, 4);
    if (u == 0) {
        float cvw = ws[OFF_VW + row];
        float pr = ws[OFF_P0R + n * MM + row] + s.x;
        float pi = ws[OFF_P0I + n * MM + row] + s.y;
        ws[row * 12 + 4 + 2 * n] = cvw * pr;
        ws[row * 12 + 5 + 2 * n] = cvw * pi;
    }
}

// atomic-fallback update (only used if ws too small for partials)
__global__ __launch_bounds__(256) void update_fallback_k(float* __restrict__ ws) {
    int i = blockIdx.x * 256 + threadIdx.x;
    float cvw = ws[OFF_VW + i];
#pragma unroll
    for (int n = 0; n < NK; n++) {
        float pr = ws[OFF_P0R + n * MM + i] + ws[OFF_YR + n * MM + i];
        float pi = ws[OFF_P0I + n * MM + i] + ws[OFF_YI + n * MM + i];
        ws[i * 12 + 4 + 2 * n] = cvw * pr;
        ws[i * 12 + 5 + 2 * n] = cvw * pi;
        ws[OFF_YR + n * MM + i] = 0.0f;
        ws[OFF_YI + n * MM + i] = 0.0f;
    }
}

// 512 blocks: (k, obs_dir, j-half). Interleaved slots:
// AR={ar0,ai0,ar1,ai1}, AI={ar2,ai2,ar3,ai3}.
__global__ __launch_bounds__(256) void far_k(const float* __restrict__ obs,
                                             const float* __restrict__ ws,
                                             float* __restrict__ out) {
    int kidx = (blockIdx.x >> 1) >> 6;
    int d = (blockIdx.x >> 1) & 63;
    int half = blockIdx.x & 1;
    float kk = 0.5f * (float)(kidx + 1);
    float ox = obs[3 * d], oy = obs[3 * d + 1], oz = obs[3 * d + 2];
    float fr = 0.0f, fi = 0.0f;
    for (int j = half * 2048 + threadIdx.x; j < half * 2048 + 2048; j += 256) {
        const float4* c4 = (const float4*)(ws + j * 12);
        float4 P = c4[0], AR = c4[1], AI = c4[2];
        float q = fmaf(P.z, oz, fmaf(P.y, oy, P.x * ox));
        float ar, ai;
        switch (kidx) {
            case 0: ar = AR.x; ai = AR.y; break;
            case 1: ar = AR.z; ai = AR.w; break;
            case 2: ar = AI.x; ai = AI.y; break;
            default: ar = AI.z; ai = AI.w; break;
        }
        float s, co;
        __sincosf(kk * q, &s, &co);
        fr += fmaf(ar, co,  ai * s);
        fi += fmaf(ai, co, -ar * s);
    }
#pragma unroll
    for (int off = 32; off > 0; off >>= 1) {
        fr += __shfl_down(fr, off);
        fi += __shfl_down(fi, off);
    }
    __shared__ float red[4][2];
    int wave = threadIdx.x >> 6;
    if ((threadIdx.x & 63) == 0) { red[wave][0] = fr; red[wave][1] = fi; }
    __syncthreads();
    if (threadIdx.x == 0) {
        fr = red[0][0] + red[1][0] + red[2][0] + red[3][0];
        fi = red[0][1] + red[1][1] + red[2][1] + red[3][1];
        atomicAdd(&out[(kidx * 64 + d) * 2 + 0], -fr);
        atomicAdd(&out[(kidx * 64 + d) * 2 + 1], -fi);
    }
}

extern "C" void kernel_launch(void* const* d_in, const int* in_sizes, int n_in,
                              void* d_out, int out_size, void* d_ws, size_t ws_size,
                              hipStream_t stream) {
    const float* V   = (const float*)d_in[0];
    const float* obs = (const float*)d_in[1];
    const float* pts = (const float*)d_in[2];
    const float* w   = (const float*)d_in[3];
    float* ws  = (float*)d_ws;
    float* out = (float*)d_out;

    // out is zeroed inside init_k (d_out re-poisoned before every call).
    init_k<<<64, 256, 0, stream>>>(V, pts, w, ws, out, out_size);
    if (ws_size >= WS_NEED_PART) {
        for (int it = 0; it < 5; it++) {
            matvec_k<NCHUNK, true><<<dim3(NCHUNK, 8), 256, 0, stream>>>(
                ws, (f2*)(ws + OFF_PART), ws + OFF_YR, ws + OFF_YI);
            reduce_update_k<NCHUNK><<<512, 256, 0, stream>>>(ws);
        }
    } else {
        for (int it = 0; it < 5; it++) {
            matvec_k<64, false><<<dim3(64, 8), 256, 0, stream>>>(
                ws, (f2*)(ws + OFF_PART), ws + OFF_YR, ws + OFF_YI);
            update_fallback_k<<<16, 256, 0, stream>>>(ws);
        }
    }
    far_k<<<512, 256, 0, stream>>>(obs, ws, out);
}